// Round 1
// baseline (579.922 us; speedup 1.0000x reference)
//
#include <hip/hip_runtime.h>
#include <cmath>

#define B_ 2
#define N_ 2048
#define C_ 128
#define H_ 8
#define D_ 16
#define CI_ 512
#define NROW 4096

__device__ __forceinline__ float sigmoidf_(float x) {
    return 1.0f / (1.0f + __expf(-x));
}

// ---------------- K1: AdaLN + 2x row-GEMV ----------------
// MODE 0 (q side): out1 = (xq@w1 + b1)*0.25 -> q[bh][n][d]; out2 = sigmoid(xq@w2) -> gate[row][c]
// MODE 1 (k side): out1 = xk@w1 -> k[bh][n][d];             out2 = xk@w2 -> v[bh][n][d]
template<int MODE>
__global__ __launch_bounds__(256)
void adaln_kernel(const float* __restrict__ x, const float* __restrict__ cond,
                  const float* __restrict__ cond_w,
                  const float* __restrict__ scale_w, const float* __restrict__ scale_b,
                  const float* __restrict__ bias_w,
                  const float* __restrict__ w1, const float* __restrict__ b1,
                  const float* __restrict__ w2,
                  float* __restrict__ out1, float* __restrict__ out2)
{
    __shared__ float xn[16][128];
    __shared__ float cn[16][128];
    __shared__ float xq[16][128];
    const int tid = threadIdx.x;
    const int row0 = blockIdx.x * 16;

    // ---- LN phase: 16 threads per row, 8 elems per thread ----
    {
        const int r = tid >> 4, p = tid & 15;
        const int row = row0 + r;
        float xv[8], cv[8];
        *(float4*)&xv[0] = *(const float4*)(x + (size_t)row * 128 + p * 8);
        *(float4*)&xv[4] = *(const float4*)(x + (size_t)row * 128 + p * 8 + 4);
        *(float4*)&cv[0] = *(const float4*)(cond + (size_t)row * 128 + p * 8);
        *(float4*)&cv[4] = *(const float4*)(cond + (size_t)row * 128 + p * 8 + 4);
        float sx = 0.f, sxx = 0.f, sc = 0.f, scc = 0.f;
#pragma unroll
        for (int ii = 0; ii < 8; ii++) {
            sx += xv[ii]; sxx += xv[ii] * xv[ii];
            sc += cv[ii]; scc += cv[ii] * cv[ii];
        }
#pragma unroll
        for (int off = 1; off < 16; off <<= 1) {
            sx += __shfl_xor(sx, off); sxx += __shfl_xor(sxx, off);
            sc += __shfl_xor(sc, off); scc += __shfl_xor(scc, off);
        }
        const float inv128 = 1.0f / 128.0f;
        float mx = sx * inv128, vx = sxx * inv128 - mx * mx;
        float rx = rsqrtf(vx + 1e-5f);
        float mc = sc * inv128, vc = scc * inv128 - mc * mc;
        float rc = rsqrtf(vc + 1e-5f);
#pragma unroll
        for (int ii = 0; ii < 8; ii++) {
            int e = p * 8 + ii;
            xn[r][e] = (xv[ii] - mx) * rx;
            cn[r][e] = (cv[ii] - mc) * rc * cond_w[e];
        }
    }
    __syncthreads();

    const int j = tid & 127, half = tid >> 7;

    // ---- phase 1: s = cn@scale_w, bvec = cn@bias_w ----
    float as[8], ab[8];
#pragma unroll
    for (int rr = 0; rr < 8; rr++) { as[rr] = 0.f; ab[rr] = 0.f; }
#pragma unroll 4
    for (int i = 0; i < 128; i++) {
        float ws = scale_w[i * 128 + j];
        float wb = bias_w[i * 128 + j];
#pragma unroll
        for (int rr = 0; rr < 8; rr++) {
            float c = cn[half * 8 + rr][i];
            as[rr] += c * ws;
            ab[rr] += c * wb;
        }
    }
    {
        float sb = scale_b[j];
#pragma unroll
        for (int rr = 0; rr < 8; rr++) {
            int r = half * 8 + rr;
            xq[r][j] = sigmoidf_(as[rr] + sb) * xn[r][j] + ab[rr];
        }
    }
    __syncthreads();

    // ---- phase 2: o1 = xq@w1, o2 = xq@w2 ----
    float o1[8], o2[8];
#pragma unroll
    for (int rr = 0; rr < 8; rr++) { o1[rr] = 0.f; o2[rr] = 0.f; }
#pragma unroll 4
    for (int i = 0; i < 128; i++) {
        float w1v = w1[i * 128 + j];
        float w2v = w2[i * 128 + j];
#pragma unroll
        for (int rr = 0; rr < 8; rr++) {
            float xv = xq[half * 8 + rr][i];
            o1[rr] += xv * w1v;
            o2[rr] += xv * w2v;
        }
    }
#pragma unroll
    for (int rr = 0; rr < 8; rr++) {
        int r = half * 8 + rr;
        int row = row0 + r;
        int b = row >> 11, n = row & 2047;
        int h = j >> 4, d = j & 15;
        size_t qkv_idx = (((size_t)b * H_ + h) * N_ + n) * D_ + d;
        if (MODE == 0) {
            out1[qkv_idx] = (o1[rr] + b1[j]) * 0.25f;                 // fold D^-0.5
            out2[(size_t)row * 128 + j] = sigmoidf_(o2[rr]);          // gate
        } else {
            out1[qkv_idx] = o1[rr];                                   // k
            out2[qkv_idx] = o2[rr];                                   // v
        }
    }
}

// ---------------- K2: flash attention (vector f32) ----------------
// grid = B*H*(N/32); 32 q-rows per block; key tiles of 64; 8 lanes per q-row
__global__ __launch_bounds__(256)
void attn_kernel(const float* __restrict__ qg, const float* __restrict__ kg,
                 const float* __restrict__ vg, const float* __restrict__ pair,
                 const float* __restrict__ gate, float* __restrict__ ao)
{
    __shared__ float Qs[32][17];
    __shared__ float Ks[64][17];
    __shared__ float Vs[64][17];
    __shared__ float Ps[32][72];
    const int tid = threadIdx.x;
    const int nqt = N_ / 32;
    const int bh = blockIdx.x / nqt;
    const int qt = blockIdx.x % nqt;
    const int b = bh >> 3, h = bh & 7;
    const int q0 = qt * 32;
    const float* qb = qg + (size_t)bh * N_ * D_;
    const float* kb = kg + (size_t)bh * N_ * D_;
    const float* vb = vg + (size_t)bh * N_ * D_;
    const float* pb = pair + (size_t)bh * N_ * N_ + (size_t)q0 * N_;

    for (int idx = tid; idx < 32 * D_; idx += 256) {
        int r = idx >> 4, d = idx & 15;
        Qs[r][d] = qb[(size_t)(q0 + r) * D_ + d];
    }
    const int g = tid >> 3, lg = tid & 7;
    float m = -1e30f, l = 0.f;
    float o[16];
#pragma unroll
    for (int d = 0; d < 16; d++) o[d] = 0.f;
    __syncthreads();
    float qr[16];
#pragma unroll
    for (int d = 0; d < 16; d++) qr[d] = Qs[g][d];

    for (int kt = 0; kt < N_ / 64; kt++) {
        __syncthreads();
        for (int idx = tid; idx < 64 * D_; idx += 256) {
            int r = idx >> 4, d = idx & 15;
            Ks[r][d] = kb[(size_t)(kt * 64 + r) * D_ + d];
            Vs[r][d] = vb[(size_t)(kt * 64 + r) * D_ + d];
        }
        for (int idx = tid; idx < 32 * 16; idx += 256) {
            int r = idx >> 4, c = idx & 15;
            float4 pv = *(const float4*)(pb + (size_t)r * N_ + kt * 64 + c * 4);
            *(float4*)&Ps[r][c * 4] = pv;
        }
        __syncthreads();

        float s[8];
        float mloc = -1e30f;
#pragma unroll
        for (int jj = 0; jj < 8; jj++) {
            int key = lg + jj * 8;
            float acc = Ps[g][key];
#pragma unroll
            for (int d = 0; d < 16; d++) acc += qr[d] * Ks[key][d];
            s[jj] = acc;
            mloc = fmaxf(mloc, acc);
        }
#pragma unroll
        for (int off = 1; off < 8; off <<= 1)
            mloc = fmaxf(mloc, __shfl_xor(mloc, off));
        float mnew = fmaxf(m, mloc);
        float f = __expf(m - mnew);
        l *= f;
#pragma unroll
        for (int d = 0; d < 16; d++) o[d] *= f;
        float ls = 0.f;
#pragma unroll
        for (int jj = 0; jj < 8; jj++) {
            float p = __expf(s[jj] - mnew);
            ls += p;
            int key = lg + jj * 8;
#pragma unroll
            for (int d = 0; d < 16; d++) o[d] += p * Vs[key][d];
        }
#pragma unroll
        for (int off = 1; off < 8; off <<= 1) ls += __shfl_xor(ls, off);
        l += ls;
        m = mnew;
    }
#pragma unroll
    for (int d = 0; d < 16; d++) {
#pragma unroll
        for (int off = 1; off < 8; off <<= 1) o[d] += __shfl_xor(o[d], off);
    }
    float inv = 1.0f / l;
    int row = b * N_ + q0 + g;
#pragma unroll
    for (int dd = 0; dd < 2; dd++) {
        int d = lg * 2 + dd;
        size_t oidx = (size_t)row * 128 + h * 16 + d;
        ao[oidx] = o[d] * inv * gate[oidx];
    }
}

// ---------------- K3a: y = x_q + sigmoid(sc@azi_wc + bc) * (ao@azi_wt) ----------------
__global__ __launch_bounds__(256)
void post_attn_kernel(const float* __restrict__ ao, const float* __restrict__ scq,
                      const float* __restrict__ xq_in,
                      const float* __restrict__ azi_wt, const float* __restrict__ azi_wc,
                      const float* __restrict__ azi_bc, float* __restrict__ y)
{
    __shared__ float aos[16][128];
    __shared__ float scs[16][128];
    const int tid = threadIdx.x;
    const int row0 = blockIdx.x * 16;
    for (int idx = tid; idx < 16 * 128; idx += 256) {
        int r = idx >> 7, c = idx & 127;
        aos[r][c] = ao[(size_t)(row0 + r) * 128 + c];
        scs[r][c] = scq[(size_t)(row0 + r) * 128 + c];
    }
    __syncthreads();
    const int j = tid & 127, half = tid >> 7;
    float at[8], ac[8];
#pragma unroll
    for (int rr = 0; rr < 8; rr++) { at[rr] = 0.f; ac[rr] = 0.f; }
#pragma unroll 4
    for (int i = 0; i < 128; i++) {
        float wt = azi_wt[i * 128 + j];
        float wc = azi_wc[i * 128 + j];
#pragma unroll
        for (int rr = 0; rr < 8; rr++) {
            at[rr] += aos[half * 8 + rr][i] * wt;
            ac[rr] += scs[half * 8 + rr][i] * wc;
        }
    }
    float bc = azi_bc[j];
#pragma unroll
    for (int rr = 0; rr < 8; rr++) {
        int row = row0 + half * 8 + rr;
        y[(size_t)row * 128 + j] = xq_in[(size_t)row * 128 + j] + sigmoidf_(ac[rr] + bc) * at[rr];
    }
}

// ---------------- K3b: transition block ----------------
__global__ __launch_bounds__(256)
void transition_kernel(const float* y, const float* __restrict__ scq,
                       const float* __restrict__ t_cond_w,
                       const float* __restrict__ t_scale_w, const float* __restrict__ t_scale_b,
                       const float* __restrict__ t_bias_w,
                       const float* __restrict__ glu1, const float* __restrict__ glu2,
                       const float* __restrict__ t_azi_wt,
                       const float* __restrict__ t_azi_wc, const float* __restrict__ t_azi_bc,
                       float* outp)
{
    __shared__ float smem[10240];
    float* yn  = smem;           // [16][128]
    float* cnb = smem + 2048;    // [16][128]
    float* scl = smem + 4096;    // [16][128]
    float* aa  = smem + 6144;    // [16][128]
    float* tg  = smem + 8192;    // [16][128]
    float* hb  = smem;           // [8][512] aliases yn+cnb (safe after P1)
    const int tid = threadIdx.x;
    const int row0 = blockIdx.x * 16;

    // ---- P0: LN(y), LN(scq)*t_cond_w, raw scq ----
    {
        const int r = tid >> 4, p = tid & 15;
        const int row = row0 + r;
        float yv[8], cv[8];
        *(float4*)&yv[0] = *(const float4*)(y + (size_t)row * 128 + p * 8);
        *(float4*)&yv[4] = *(const float4*)(y + (size_t)row * 128 + p * 8 + 4);
        *(float4*)&cv[0] = *(const float4*)(scq + (size_t)row * 128 + p * 8);
        *(float4*)&cv[4] = *(const float4*)(scq + (size_t)row * 128 + p * 8 + 4);
        float sy = 0.f, syy = 0.f, sc = 0.f, scc = 0.f;
#pragma unroll
        for (int ii = 0; ii < 8; ii++) {
            sy += yv[ii]; syy += yv[ii] * yv[ii];
            sc += cv[ii]; scc += cv[ii] * cv[ii];
        }
#pragma unroll
        for (int off = 1; off < 16; off <<= 1) {
            sy += __shfl_xor(sy, off); syy += __shfl_xor(syy, off);
            sc += __shfl_xor(sc, off); scc += __shfl_xor(scc, off);
        }
        const float inv128 = 1.0f / 128.0f;
        float my = sy * inv128, vy = syy * inv128 - my * my;
        float ry = rsqrtf(vy + 1e-5f);
        float mc = sc * inv128, vc = scc * inv128 - mc * mc;
        float rc = rsqrtf(vc + 1e-5f);
#pragma unroll
        for (int ii = 0; ii < 8; ii++) {
            int e = p * 8 + ii;
            yn[r * 128 + e] = (yv[ii] - my) * ry;
            cnb[r * 128 + e] = (cv[ii] - mc) * rc * t_cond_w[e];
            scl[r * 128 + e] = cv[ii];
        }
    }
    __syncthreads();

    const int j = tid & 127, half = tid >> 7;

    // ---- P1: cn@t_scale_w, cn@t_bias_w, scq@t_azi_wc ----
    {
        float as[8], ab[8], ac[8];
#pragma unroll
        for (int rr = 0; rr < 8; rr++) { as[rr] = 0.f; ab[rr] = 0.f; ac[rr] = 0.f; }
#pragma unroll 4
        for (int i = 0; i < 128; i++) {
            float ws = t_scale_w[i * 128 + j];
            float wb = t_bias_w[i * 128 + j];
            float wc = t_azi_wc[i * 128 + j];
#pragma unroll
            for (int rr = 0; rr < 8; rr++) {
                float cv = cnb[(half * 8 + rr) * 128 + i];
                float sv = scl[(half * 8 + rr) * 128 + i];
                as[rr] += cv * ws;
                ab[rr] += cv * wb;
                ac[rr] += sv * wc;
            }
        }
        float sbv = t_scale_b[j], tbv = t_azi_bc[j];
#pragma unroll
        for (int rr = 0; rr < 8; rr++) {
            int r = half * 8 + rr;
            aa[r * 128 + j] = sigmoidf_(as[rr] + sbv) * yn[r * 128 + j] + ab[rr];
            tg[r * 128 + j] = sigmoidf_(ac[rr] + tbv);
        }
    }
    __syncthreads();

    // ---- P2/P3: SwiGLU + t_azi_wt, 8 rows per pass ----
    for (int rp = 0; rp < 2; rp++) {
        float h1a[8], h1b[8], h2a[8], h2b[8];
#pragma unroll
        for (int rr = 0; rr < 8; rr++) { h1a[rr] = 0.f; h1b[rr] = 0.f; h2a[rr] = 0.f; h2b[rr] = 0.f; }
        const int c0 = tid, c1 = tid + 256;
#pragma unroll 2
        for (int i = 0; i < 128; i++) {
            float g1a = glu1[i * 512 + c0];
            float g1b = glu1[i * 512 + c1];
            float g2a = glu2[i * 512 + c0];
            float g2b = glu2[i * 512 + c1];
#pragma unroll
            for (int rr = 0; rr < 8; rr++) {
                float av = aa[(rp * 8 + rr) * 128 + i];
                h1a[rr] += av * g1a;
                h1b[rr] += av * g1b;
                h2a[rr] += av * g2a;
                h2b[rr] += av * g2b;
            }
        }
        __syncthreads();   // previous readers of hb are done
#pragma unroll
        for (int rr = 0; rr < 8; rr++) {
            hb[rr * 512 + c0] = h1a[rr] * sigmoidf_(h1a[rr]) * h2a[rr];
            hb[rr * 512 + c1] = h1b[rr] * sigmoidf_(h1b[rr]) * h2b[rr];
        }
        __syncthreads();

        float acc[4];
#pragma unroll
        for (int qq = 0; qq < 4; qq++) acc[qq] = 0.f;
        const int qh = half * 4;
#pragma unroll 4
        for (int i = 0; i < 512; i++) {
            float w = t_azi_wt[i * 128 + j];
#pragma unroll
            for (int qq = 0; qq < 4; qq++) acc[qq] += hb[(qh + qq) * 512 + i] * w;
        }
#pragma unroll
        for (int qq = 0; qq < 4; qq++) {
            int rl = rp * 8 + qh + qq;
            int row = row0 + rl;
            outp[(size_t)row * 128 + j] = y[(size_t)row * 128 + j] + tg[rl * 128 + j] * acc[qq];
        }
        __syncthreads();   // protect hb before next pass overwrites
    }
}

extern "C" void kernel_launch(void* const* d_in, const int* in_sizes, int n_in,
                              void* d_out, int out_size, void* d_ws, size_t ws_size,
                              hipStream_t stream)
{
    (void)in_sizes; (void)n_in; (void)out_size; (void)ws_size;
    const float* x_q      = (const float*)d_in[0];
    const float* x_k      = (const float*)d_in[1];
    const float* pair     = (const float*)d_in[4];
    const float* scq      = (const float*)d_in[5];
    const float* sck      = (const float*)d_in[6];
    const float* q_cond_w = (const float*)d_in[7];
    const float* q_scale_w= (const float*)d_in[8];
    const float* q_scale_b= (const float*)d_in[9];
    const float* q_bias_w = (const float*)d_in[10];
    const float* k_cond_w = (const float*)d_in[11];
    const float* k_scale_w= (const float*)d_in[12];
    const float* k_scale_b= (const float*)d_in[13];
    const float* k_bias_w = (const float*)d_in[14];
    const float* wq       = (const float*)d_in[15];
    const float* bq       = (const float*)d_in[16];
    const float* wk       = (const float*)d_in[17];
    const float* wv       = (const float*)d_in[18];
    const float* wg       = (const float*)d_in[19];
    const float* azi_wt   = (const float*)d_in[20];
    const float* azi_wc   = (const float*)d_in[21];
    const float* azi_bc   = (const float*)d_in[22];
    const float* t_cond_w = (const float*)d_in[23];
    const float* t_scale_w= (const float*)d_in[24];
    const float* t_scale_b= (const float*)d_in[25];
    const float* t_bias_w = (const float*)d_in[26];
    const float* glu1     = (const float*)d_in[27];
    const float* glu2     = (const float*)d_in[28];
    const float* t_azi_wt = (const float*)d_in[29];
    const float* t_azi_wc = (const float*)d_in[30];
    const float* t_azi_bc = (const float*)d_in[31];

    float* out = (float*)d_out;
    float* ws  = (float*)d_ws;
    float* qs   = ws;                 // 524288 f32 (2MB) [b][h][n][d]
    float* ks   = ws + 524288;        // 2MB
    float* vs   = ws + 1048576;       // 2MB
    float* gate = ws + 1572864;       // 2MB [row][c]
    float* ao   = ws + 2097152;       // 2MB [row][c] (gated attention out)
    float* y    = out;                // y lives in d_out; overwritten by transition

    adaln_kernel<0><<<NROW / 16, 256, 0, stream>>>(
        x_q, scq, q_cond_w, q_scale_w, q_scale_b, q_bias_w, wq, bq, wg, qs, gate);
    adaln_kernel<1><<<NROW / 16, 256, 0, stream>>>(
        x_k, sck, k_cond_w, k_scale_w, k_scale_b, k_bias_w, wk, nullptr, wv, ks, vs);
    attn_kernel<<<B_ * H_ * (N_ / 32), 256, 0, stream>>>(qs, ks, vs, pair, gate, ao);
    post_attn_kernel<<<NROW / 16, 256, 0, stream>>>(ao, scq, x_q, azi_wt, azi_wc, azi_bc, y);
    transition_kernel<<<NROW / 16, 256, 0, stream>>>(
        y, scq, t_cond_w, t_scale_w, t_scale_b, t_bias_w, glu1, glu2,
        t_azi_wt, t_azi_wc, t_azi_bc, out);
}

// Round 2
// 174.902 us; speedup vs baseline: 3.3157x; 3.3157x over previous
//
#include <hip/hip_runtime.h>
#include <cmath>

#define B_ 2
#define N_ 2048
#define C_ 128
#define H_ 8
#define D_ 16
#define CI_ 512
#define NROW 4096

typedef float f32x4 __attribute__((ext_vector_type(4)));
typedef short bf16x4 __attribute__((ext_vector_type(4)));

__device__ __forceinline__ float sigmoidf_(float x) {
    return 1.0f / (1.0f + __expf(-x));
}

__device__ __forceinline__ unsigned short f2bf(float x) {
    union { float f; unsigned int u; } v; v.f = x;
    unsigned int r = v.u + 0x7fffu + ((v.u >> 16) & 1u);
    return (unsigned short)(r >> 16);
}

__device__ __forceinline__ f32x4 mfma16(bf16x4 a, bf16x4 b, f32x4 c) {
#if __has_builtin(__builtin_amdgcn_mfma_f32_16x16x16bf16_1k)
    return __builtin_amdgcn_mfma_f32_16x16x16bf16_1k(a, b, c, 0, 0, 0);
#else
    asm("v_mfma_f32_16x16x16_bf16 %0, %1, %2, %0\n\ts_nop 7\n\ts_nop 3"
        : "+v"(c) : "v"(a), "v"(b));
    return c;
#endif
}

// ---------------- K1: AdaLN + 2x row-GEMV (1024 thr, 16 rows/block) ----------------
// MODE 0: out1 = bf16((xq@w1 + b1)*0.25) -> q[bh][n][d]; out2 = f32 sigmoid(xq@w2) gate[row][c]
// MODE 1: out1 = bf16(xk@w1) -> k[bh][n][d];             out2 = bf16(xk@w2) -> vt[bh][d][n]
template<int MODE>
__global__ __launch_bounds__(1024)
void adaln_kernel(const float* __restrict__ x, const float* __restrict__ cond,
                  const float* __restrict__ cond_w,
                  const float* __restrict__ scale_w, const float* __restrict__ scale_b,
                  const float* __restrict__ bias_w,
                  const float* __restrict__ w1, const float* __restrict__ b1,
                  const float* __restrict__ w2,
                  unsigned short* __restrict__ out1, void* __restrict__ out2v)
{
    __shared__ float xn[16][128];
    __shared__ float cn[16][128];
    __shared__ float xq[16][128];
    const int tid = threadIdx.x;
    const int row0 = blockIdx.x * 16;

    {   // LN phase: one wave per row, 2 elems per thread
        const int r = tid >> 6, p = tid & 63;
        const size_t base = (size_t)(row0 + r) * 128 + p * 2;
        float2 xv = *(const float2*)(x + base);
        float2 cv = *(const float2*)(cond + base);
        float sx = xv.x + xv.y, sxx = xv.x * xv.x + xv.y * xv.y;
        float sc = cv.x + cv.y, scc = cv.x * cv.x + cv.y * cv.y;
#pragma unroll
        for (int off = 1; off < 64; off <<= 1) {
            sx += __shfl_xor(sx, off); sxx += __shfl_xor(sxx, off);
            sc += __shfl_xor(sc, off); scc += __shfl_xor(scc, off);
        }
        const float inv = 1.0f / 128.0f;
        float mx = sx * inv, vx = sxx * inv - mx * mx, rx = rsqrtf(vx + 1e-5f);
        float mc = sc * inv, vc = scc * inv - mc * mc, rc = rsqrtf(vc + 1e-5f);
        xn[r][p * 2]     = (xv.x - mx) * rx;
        xn[r][p * 2 + 1] = (xv.y - mx) * rx;
        cn[r][p * 2]     = (cv.x - mc) * rc * cond_w[p * 2];
        cn[r][p * 2 + 1] = (cv.y - mc) * rc * cond_w[p * 2 + 1];
    }
    __syncthreads();

    const int j = tid & 127, grp = tid >> 7, r0 = grp * 2;

    {   // phase 1: adaptive scale/bias
        float as0 = 0, as1 = 0, ab0 = 0, ab1 = 0;
#pragma unroll 4
        for (int i = 0; i < 128; i++) {
            float ws = scale_w[i * 128 + j], wb = bias_w[i * 128 + j];
            float c0 = cn[r0][i], c1 = cn[r0 + 1][i];
            as0 += c0 * ws; as1 += c1 * ws;
            ab0 += c0 * wb; ab1 += c1 * wb;
        }
        float sb = scale_b[j];
        xq[r0][j]     = sigmoidf_(as0 + sb) * xn[r0][j] + ab0;
        xq[r0 + 1][j] = sigmoidf_(as1 + sb) * xn[r0 + 1][j] + ab1;
    }
    __syncthreads();

    float o10 = 0, o11 = 0, o20 = 0, o21 = 0;
#pragma unroll 4
    for (int i = 0; i < 128; i++) {
        float wa = w1[i * 128 + j], wb = w2[i * 128 + j];
        float x0 = xq[r0][i], x1 = xq[r0 + 1][i];
        o10 += x0 * wa; o11 += x1 * wa;
        o20 += x0 * wb; o21 += x1 * wb;
    }
    const int h = j >> 4, d = j & 15;
    const int row = row0 + r0;
    const int b = row >> 11, n = row & 2047;
    size_t qi = (((size_t)b * 8 + h) * 2048 + n) * 16 + d;
    if (MODE == 0) {
        float bqv = b1[j];
        out1[qi]      = f2bf((o10 + bqv) * 0.25f);
        out1[qi + 16] = f2bf((o11 + bqv) * 0.25f);
        float* gate = (float*)out2v;
        gate[(size_t)row * 128 + j]       = sigmoidf_(o20);
        gate[(size_t)(row + 1) * 128 + j] = sigmoidf_(o21);
    } else {
        out1[qi]      = f2bf(o10);
        out1[qi + 16] = f2bf(o11);
        unsigned short* vt = (unsigned short*)out2v;
        size_t vbase = (((size_t)b * 8 + h) * 16 + d) * 2048 + n;
        unsigned int packed = (unsigned int)f2bf(o20) | ((unsigned int)f2bf(o21) << 16);
        *(unsigned int*)(vt + vbase) = packed;   // n even -> aligned
    }
}

// ---------------- K2: MFMA flash attention, 1 wave / 16 q-rows ----------------
// S^T = K·Q^T (pair as C-init); P lane-local -> PV A-fragment directly.
__global__ __launch_bounds__(64)
void attn_kernel(const unsigned short* __restrict__ qg, const unsigned short* __restrict__ kg,
                 const unsigned short* __restrict__ vtg, const float* __restrict__ pair,
                 const float* __restrict__ gate, float* __restrict__ ao)
{
    __shared__ float P[16][68];
    const int l = threadIdx.x;
    const int g = l >> 4, q = l & 15;
    const int qt = blockIdx.x & 127;        // N/16
    const int bh = blockIdx.x >> 7;         // 0..15
    const int b = bh >> 3, h = bh & 7;
    const int q0 = qt * 16;

    const unsigned short* qb = qg + ((size_t)bh * 2048 + q0 + q) * 16 + 4 * g;
    const unsigned short* kb = kg + ((size_t)bh * 2048 + q) * 16 + 4 * g;
    const unsigned short* vb = vtg + ((size_t)bh * 16 + q) * 2048 + 4 * g;
    const float* pb = pair + (size_t)bh * N_ * N_ + (size_t)(q0 + g) * N_ + q * 4;

    bf16x4 qf = *(const bf16x4*)qb;

    f32x4 o = {0.f, 0.f, 0.f, 0.f};
    float m = -1e30f, lsum = 0.f;

    f32x4 p0[4], p1[4], p2[4], p3[4];
    bf16x4 k0[4], v0[4], k1[4], v1[4];

    auto issue_pair = [&](f32x4 (&pr)[4], int kt) {
        const float* pt = pb + kt * 64;
#pragma unroll
        for (int i = 0; i < 4; i++)
            pr[i] = *(const f32x4*)(pt + (size_t)(4 * i) * N_);
    };
    auto issue_kv = [&](bf16x4 (&kf)[4], bf16x4 (&vf)[4], int kt) {
#pragma unroll
        for (int t = 0; t < 4; t++) {
            kf[t] = *(const bf16x4*)(kb + (size_t)(kt * 64 + t * 16) * 16);
            vf[t] = *(const bf16x4*)(vb + kt * 64 + t * 16);
        }
    };
    auto step = [&](f32x4 (&pr)[4], bf16x4 (&kf)[4], bf16x4 (&vf)[4]) {
#pragma unroll
        for (int i = 0; i < 4; i++)
            *(f32x4*)&P[g + 4 * i][q * 4] = pr[i];
        asm volatile("s_waitcnt lgkmcnt(0)" ::: "memory");
        __builtin_amdgcn_sched_barrier(0);
        f32x4 s[4];
#pragma unroll
        for (int t = 0; t < 4; t++) {
            f32x4 c = *(const f32x4*)&P[q][t * 16 + 4 * g];
            s[t] = mfma16(kf[t], qf, c);   // S^T tile: col=q(l&15), row=key(4g+reg)
        }
        float mloc = s[0][0];
#pragma unroll
        for (int t = 0; t < 4; t++)
#pragma unroll
            for (int r = 0; r < 4; r++) mloc = fmaxf(mloc, s[t][r]);
        mloc = fmaxf(mloc, __shfl_xor(mloc, 16));
        mloc = fmaxf(mloc, __shfl_xor(mloc, 32));
        float mnew = fmaxf(m, mloc);
        float fsc = __expf(m - mnew);
        m = mnew;
        lsum *= fsc;
        // o rows are q=4g+r; fetch that row's rescale factor
#pragma unroll
        for (int r = 0; r < 4; r++) {
            float fr = __shfl(fsc, 4 * g + r);
            o[r] *= fr;
        }
        bf16x4 pf[4];
#pragma unroll
        for (int t = 0; t < 4; t++) {
#pragma unroll
            for (int r = 0; r < 4; r++) {
                float p = __expf(s[t][r] - mnew);
                lsum += p;
                pf[t][r] = (short)f2bf(p);
            }
        }
#pragma unroll
        for (int t = 0; t < 4; t++)
            o = mfma16(pf[t], vf[t], o);   // O: col=d(l&15), row=q(4g+reg)
    };

    issue_pair(p0, 0); issue_pair(p1, 1); issue_pair(p2, 2); issue_pair(p3, 3);
    issue_kv(k0, v0, 0); issue_kv(k1, v1, 1);

    for (int kt = 0; kt < 32; kt += 4) {
        step(p0, k0, v0);
        if (kt + 4 < 32) issue_pair(p0, kt + 4);
        if (kt + 2 < 32) issue_kv(k0, v0, kt + 2);
        step(p1, k1, v1);
        if (kt + 5 < 32) issue_pair(p1, kt + 5);
        if (kt + 3 < 32) issue_kv(k1, v1, kt + 3);
        step(p2, k0, v0);
        if (kt + 6 < 32) issue_pair(p2, kt + 6);
        if (kt + 4 < 32) issue_kv(k0, v0, kt + 4);
        step(p3, k1, v1);
        if (kt + 7 < 32) issue_pair(p3, kt + 7);
        if (kt + 5 < 32) issue_kv(k1, v1, kt + 5);
    }

    lsum += __shfl_xor(lsum, 16);
    lsum += __shfl_xor(lsum, 32);
    const size_t orow0 = (size_t)b * 2048 + q0;
#pragma unroll
    for (int r = 0; r < 4; r++) {
        float li = __shfl(lsum, 4 * g + r);
        size_t idx = (orow0 + 4 * g + r) * 128 + h * 16 + q;
        ao[idx] = o[r] * (1.0f / li) * gate[idx];
    }
}

// ---------------- K3a: y = x_q + sigmoid(sc@azi_wc + bc) * (ao@azi_wt) ----------------
__global__ __launch_bounds__(1024)
void post_attn_kernel(const float* __restrict__ ao, const float* __restrict__ scq,
                      const float* __restrict__ xq_in,
                      const float* __restrict__ azi_wt, const float* __restrict__ azi_wc,
                      const float* __restrict__ azi_bc, float* __restrict__ yout)
{
    __shared__ float aos[16][128];
    __shared__ float scs[16][128];
    const int tid = threadIdx.x;
    const int row0 = blockIdx.x * 16;
    {
        const int r = tid >> 6, p = tid & 63;
        const size_t base = (size_t)(row0 + r) * 128 + p * 2;
        *(float2*)&aos[r][p * 2] = *(const float2*)(ao + base);
        *(float2*)&scs[r][p * 2] = *(const float2*)(scq + base);
    }
    __syncthreads();
    const int j = tid & 127, grp = tid >> 7, r0 = grp * 2;
    float at0 = 0, at1 = 0, ac0 = 0, ac1 = 0;
#pragma unroll 4
    for (int i = 0; i < 128; i++) {
        float wt = azi_wt[i * 128 + j], wc = azi_wc[i * 128 + j];
        at0 += aos[r0][i] * wt;   at1 += aos[r0 + 1][i] * wt;
        ac0 += scs[r0][i] * wc;   ac1 += scs[r0 + 1][i] * wc;
    }
    float bc = azi_bc[j];
    size_t b0 = (size_t)(row0 + r0) * 128 + j;
    yout[b0]       = xq_in[b0]       + sigmoidf_(ac0 + bc) * at0;
    yout[b0 + 128] = xq_in[b0 + 128] + sigmoidf_(ac1 + bc) * at1;
}

// ---------------- K3b: transition block (1024 thr) ----------------
__global__ __launch_bounds__(1024)
void transition_kernel(const float* y, const float* __restrict__ scq,
                       const float* __restrict__ t_cond_w,
                       const float* __restrict__ t_scale_w, const float* __restrict__ t_scale_b,
                       const float* __restrict__ t_bias_w,
                       const float* __restrict__ glu1, const float* __restrict__ glu2,
                       const float* __restrict__ t_azi_wt,
                       const float* __restrict__ t_azi_wc, const float* __restrict__ t_azi_bc,
                       float* outp)
{
    __shared__ float aa[16][128];
    __shared__ float tg[16][128];
    __shared__ float big[8192];          // yn|cnb|scl during P0/P1, then hb[16][512]
    float* yn  = big;
    float* cnb = big + 2048;
    float* scl = big + 4096;
    float* hb  = big;
    const int tid = threadIdx.x;
    const int row0 = blockIdx.x * 16;

    {   // P0: LN(y), LN(scq)*w, raw scq
        const int r = tid >> 6, p = tid & 63;
        const size_t base = (size_t)(row0 + r) * 128 + p * 2;
        float2 yv = *(const float2*)(y + base);
        float2 cv = *(const float2*)(scq + base);
        float sy = yv.x + yv.y, syy = yv.x * yv.x + yv.y * yv.y;
        float sc = cv.x + cv.y, scc = cv.x * cv.x + cv.y * cv.y;
#pragma unroll
        for (int off = 1; off < 64; off <<= 1) {
            sy += __shfl_xor(sy, off); syy += __shfl_xor(syy, off);
            sc += __shfl_xor(sc, off); scc += __shfl_xor(scc, off);
        }
        const float inv = 1.0f / 128.0f;
        float my = sy * inv, vy = syy * inv - my * my, ry = rsqrtf(vy + 1e-5f);
        float mc = sc * inv, vc = scc * inv - mc * mc, rc = rsqrtf(vc + 1e-5f);
        yn[r * 128 + p * 2]      = (yv.x - my) * ry;
        yn[r * 128 + p * 2 + 1]  = (yv.y - my) * ry;
        cnb[r * 128 + p * 2]     = (cv.x - mc) * rc * t_cond_w[p * 2];
        cnb[r * 128 + p * 2 + 1] = (cv.y - mc) * rc * t_cond_w[p * 2 + 1];
        scl[r * 128 + p * 2]     = cv.x;
        scl[r * 128 + p * 2 + 1] = cv.y;
    }
    __syncthreads();
    const int j = tid & 127, grp = tid >> 7, r0 = grp * 2;

    {   // P1: adaptive scale/bias + transition gate
        float as0 = 0, as1 = 0, ab0 = 0, ab1 = 0, ac0 = 0, ac1 = 0;
#pragma unroll 4
        for (int i = 0; i < 128; i++) {
            float ws = t_scale_w[i * 128 + j], wb = t_bias_w[i * 128 + j], wc = t_azi_wc[i * 128 + j];
            float c0 = cnb[r0 * 128 + i], c1 = cnb[(r0 + 1) * 128 + i];
            float s0 = scl[r0 * 128 + i], s1 = scl[(r0 + 1) * 128 + i];
            as0 += c0 * ws; as1 += c1 * ws;
            ab0 += c0 * wb; ab1 += c1 * wb;
            ac0 += s0 * wc; ac1 += s1 * wc;
        }
        float sb = t_scale_b[j], tb = t_azi_bc[j];
        aa[r0][j]     = sigmoidf_(as0 + sb) * yn[r0 * 128 + j] + ab0;
        aa[r0 + 1][j] = sigmoidf_(as1 + sb) * yn[(r0 + 1) * 128 + j] + ab1;
        tg[r0][j]     = sigmoidf_(ac0 + tb);
        tg[r0 + 1][j] = sigmoidf_(ac1 + tb);
    }
    __syncthreads();

    {   // P2: SwiGLU 128->512 (hb overlays yn/cnb/scl)
        const int c = tid & 511, rg = tid >> 9;
        float h1[8], h2[8];
#pragma unroll
        for (int rr = 0; rr < 8; rr++) { h1[rr] = 0; h2[rr] = 0; }
#pragma unroll 2
        for (int i = 0; i < 128; i++) {
            float g1 = glu1[i * 512 + c], g2 = glu2[i * 512 + c];
#pragma unroll
            for (int rr = 0; rr < 8; rr++) {
                float av = aa[rg * 8 + rr][i];
                h1[rr] += av * g1; h2[rr] += av * g2;
            }
        }
#pragma unroll
        for (int rr = 0; rr < 8; rr++)
            hb[(rg * 8 + rr) * 512 + c] = h1[rr] * sigmoidf_(h1[rr]) * h2[rr];
    }
    __syncthreads();

    {   // P3: 512->128 + zero-init gate + residual
        float a0 = 0, a1 = 0;
#pragma unroll 8
        for (int i = 0; i < 512; i++) {
            float w = t_azi_wt[i * 128 + j];
            a0 += hb[r0 * 512 + i] * w;
            a1 += hb[(r0 + 1) * 512 + i] * w;
        }
        size_t b0 = (size_t)(row0 + r0) * 128 + j;
        outp[b0]       = y[b0]       + tg[r0][j] * a0;
        outp[b0 + 128] = y[b0 + 128] + tg[r0 + 1][j] * a1;
    }
}

extern "C" void kernel_launch(void* const* d_in, const int* in_sizes, int n_in,
                              void* d_out, int out_size, void* d_ws, size_t ws_size,
                              hipStream_t stream)
{
    (void)in_sizes; (void)n_in; (void)out_size; (void)ws_size;
    const float* x_q      = (const float*)d_in[0];
    const float* x_k      = (const float*)d_in[1];
    const float* pair     = (const float*)d_in[4];
    const float* scq      = (const float*)d_in[5];
    const float* sck      = (const float*)d_in[6];
    const float* q_cond_w = (const float*)d_in[7];
    const float* q_scale_w= (const float*)d_in[8];
    const float* q_scale_b= (const float*)d_in[9];
    const float* q_bias_w = (const float*)d_in[10];
    const float* k_cond_w = (const float*)d_in[11];
    const float* k_scale_w= (const float*)d_in[12];
    const float* k_scale_b= (const float*)d_in[13];
    const float* k_bias_w = (const float*)d_in[14];
    const float* wq       = (const float*)d_in[15];
    const float* bq       = (const float*)d_in[16];
    const float* wk       = (const float*)d_in[17];
    const float* wv       = (const float*)d_in[18];
    const float* wg       = (const float*)d_in[19];
    const float* azi_wt   = (const float*)d_in[20];
    const float* azi_wc   = (const float*)d_in[21];
    const float* azi_bc   = (const float*)d_in[22];
    const float* t_cond_w = (const float*)d_in[23];
    const float* t_scale_w= (const float*)d_in[24];
    const float* t_scale_b= (const float*)d_in[25];
    const float* t_bias_w = (const float*)d_in[26];
    const float* glu1     = (const float*)d_in[27];
    const float* glu2     = (const float*)d_in[28];
    const float* t_azi_wt = (const float*)d_in[29];
    const float* t_azi_wc = (const float*)d_in[30];
    const float* t_azi_bc = (const float*)d_in[31];

    float* out = (float*)d_out;
    unsigned short* qs = (unsigned short*)d_ws;        // bf16 [bh][n][16]   1MB
    unsigned short* ks = qs + 524288;                  // bf16 [bh][n][16]   1MB
    unsigned short* vt = ks + 524288;                  // bf16 [bh][d][n]    1MB
    float* gate = (float*)(vt + 524288);               // f32 [row][128]     2MB
    float* aob  = gate + 524288;                       // f32 [row][128]     2MB

    adaln_kernel<0><<<NROW / 16, 1024, 0, stream>>>(
        x_q, scq, q_cond_w, q_scale_w, q_scale_b, q_bias_w, wq, bq, wg, qs, (void*)gate);
    adaln_kernel<1><<<NROW / 16, 1024, 0, stream>>>(
        x_k, sck, k_cond_w, k_scale_w, k_scale_b, k_bias_w, wk, nullptr, wv, ks, (void*)vt);
    attn_kernel<<<B_ * H_ * (N_ / 16), 64, 0, stream>>>(qs, ks, vt, pair, gate, aob);
    post_attn_kernel<<<NROW / 16, 1024, 0, stream>>>(aob, scq, x_q, azi_wt, azi_wc, azi_bc, out);
    transition_kernel<<<NROW / 16, 1024, 0, stream>>>(
        out, scq, t_cond_w, t_scale_w, t_scale_b, t_bias_w, glu1, glu2,
        t_azi_wt, t_azi_wc, t_azi_bc, out);
}

// Round 3
// 135.383 us; speedup vs baseline: 4.2836x; 1.2919x over previous
//
#include <hip/hip_runtime.h>
#include <cmath>

#define B_ 2
#define N_ 2048
#define C_ 128
#define H_ 8
#define D_ 16
#define CI_ 512
#define NROW 4096

typedef float f32x4 __attribute__((ext_vector_type(4)));
typedef short bf16x4 __attribute__((ext_vector_type(4)));
typedef unsigned short u16;

__device__ __forceinline__ float sigmoidf_(float x) {
    return 1.0f / (1.0f + __expf(-x));
}

__device__ __forceinline__ u16 f2bf(float x) {
    union { float f; unsigned int u; } v; v.f = x;
    unsigned int r = v.u + 0x7fffu + ((v.u >> 16) & 1u);
    return (u16)(r >> 16);
}

__device__ __forceinline__ float bf2f(u16 b) {
    union { unsigned int u; float f; } v; v.u = ((unsigned int)b) << 16;
    return v.f;
}

__device__ __forceinline__ f32x4 mfma16(bf16x4 a, bf16x4 b, f32x4 c) {
#if __has_builtin(__builtin_amdgcn_mfma_f32_16x16x16bf16_1k)
    return __builtin_amdgcn_mfma_f32_16x16x16bf16_1k(a, b, c, 0, 0, 0);
#else
    asm("v_mfma_f32_16x16x16_bf16 %0, %1, %2, %0\n\ts_nop 7\n\ts_nop 3"
        : "+v"(c) : "v"(a), "v"(b));
    return c;
#endif
}

// Weight^T (bf16) region offsets, in u16 elements
#define WT_QS    0         // q_scale_w^T   [128][128]
#define WT_QB    16384     // q_bias_w^T
#define WT_WQ    32768
#define WT_WG    49152
#define WT_KS    65536
#define WT_KB    81920
#define WT_WK    98304
#define WT_WV    114688
#define WT_AZIT  131072    // azi_wt^T
#define WT_AZIC  147456    // azi_wc^T
#define WT_TS    163840    // t_scale_w^T
#define WT_TB    180224    // t_bias_w^T
#define WT_TAZIC 196608    // t_azi_wc^T
#define WT_GLU1  212992    // glu1^T [512][128]
#define WT_GLU2  278528    // glu2^T [512][128]
#define WT_TAZIT 344064    // t_azi_wt^T [128][512]
#define WT_TOTAL 409600

// ---------------- K0: transpose + convert weights to bf16 ----------------
__global__ __launch_bounds__(256)
void prep_kernel(const float* qs_w, const float* qb_w, const float* wq, const float* wg,
                 const float* ks_w, const float* kb_w, const float* wk, const float* wv,
                 const float* azi_wt, const float* azi_wc, const float* ts_w, const float* tb_w,
                 const float* tazi_wc, const float* glu1, const float* glu2, const float* tazi_wt,
                 u16* wT)
{
    __shared__ float tile[16][132];
    const float* src; int sld, sr0, sc0; u16* dst; int dld, dr0, dc0;
    int bi = blockIdx.x;
    if (bi < 13) {
        const float* srcs[13] = {qs_w, qb_w, wq, wg, ks_w, kb_w, wk, wv,
                                 azi_wt, azi_wc, ts_w, tb_w, tazi_wc};
        src = srcs[bi]; sld = 128; sr0 = 0; sc0 = 0;
        dst = wT + bi * 16384; dld = 128; dr0 = 0; dc0 = 0;
    } else if (bi < 17) {
        int c = (bi - 13) * 128;
        src = glu1; sld = 512; sr0 = 0; sc0 = c;
        dst = wT + WT_GLU1; dld = 128; dr0 = c; dc0 = 0;
    } else if (bi < 21) {
        int c = (bi - 17) * 128;
        src = glu2; sld = 512; sr0 = 0; sc0 = c;
        dst = wT + WT_GLU2; dld = 128; dr0 = c; dc0 = 0;
    } else {
        int r = (bi - 21) * 128;
        src = tazi_wt; sld = 128; sr0 = r; sc0 = 0;
        dst = wT + WT_TAZIT; dld = 512; dr0 = 0; dc0 = r;
    }
    const int t = threadIdx.x;
    const int lr = t >> 4, lc = (t & 15) * 8;
    const int wj = t >> 1, wih = t & 1;
    for (int p = 0; p < 8; p++) {
        const float* sp = src + (size_t)(sr0 + p * 16 + lr) * sld + sc0 + lc;
        *(float4*)&tile[lr][lc]     = *(const float4*)sp;
        *(float4*)&tile[lr][lc + 4] = *(const float4*)(sp + 4);
        __syncthreads();
        unsigned pk[4];
#pragma unroll
        for (int u2 = 0; u2 < 4; u2++) {
            u16 lo = f2bf(tile[wih * 8 + u2 * 2][wj]);
            u16 hi = f2bf(tile[wih * 8 + u2 * 2 + 1][wj]);
            pk[u2] = (unsigned)lo | ((unsigned)hi << 16);
        }
        *(uint4*)(dst + (size_t)(dr0 + wj) * dld + dc0 + p * 16 + wih * 8) = *(uint4*)pk;
        __syncthreads();
    }
}

// ---------------- K1: fused AdaLN + projections, MFMA (q & k sides) ----------------
// grid 512: blocks 0..255 = q-side (q + gate), 256..511 = k-side (k + v^T)
__global__ __launch_bounds__(128)
void adaln_mfma(const float* __restrict__ x_q, const float* __restrict__ scq,
                const float* __restrict__ x_k, const float* __restrict__ sck,
                const float* __restrict__ q_cond_w, const float* __restrict__ q_scale_b,
                const float* __restrict__ bq,
                const float* __restrict__ k_cond_w, const float* __restrict__ k_scale_b,
                const u16* __restrict__ wT,
                u16* __restrict__ qs, u16* __restrict__ ks, u16* __restrict__ vt,
                float* __restrict__ gate)
{
    __shared__ u16 xn[16][132];
    __shared__ u16 cn[16][132];
    __shared__ u16 xq[16][132];
    __shared__ u16 vls[128][20];
    const int bi = blockIdx.x;
    const int qside = (bi < 256) ? 1 : 0;
    const int rowblk = (bi & 255) * 16;
    const float* xin = qside ? x_q : x_k;
    const float* cin = qside ? scq : sck;
    const float* cw  = qside ? q_cond_w : k_cond_w;
    const float* slb = qside ? q_scale_b : k_scale_b;
    const u16* Wsc = wT + (qside ? WT_QS : WT_KS);
    const u16* Wbi = wT + (qside ? WT_QB : WT_KB);
    const u16* W1  = wT + (qside ? WT_WQ : WT_WK);
    const u16* W2  = wT + (qside ? WT_WG : WT_WV);

    const int t = threadIdx.x;
    {   // LN: 8 lanes per row, 16 elems per lane
        const int r = t >> 3, p8 = t & 7;
        const size_t base = (size_t)(rowblk + r) * 128 + p8 * 16;
        float xv[16], cv[16];
        *(float4*)&xv[0]  = *(const float4*)(xin + base);
        *(float4*)&xv[4]  = *(const float4*)(xin + base + 4);
        *(float4*)&xv[8]  = *(const float4*)(xin + base + 8);
        *(float4*)&xv[12] = *(const float4*)(xin + base + 12);
        *(float4*)&cv[0]  = *(const float4*)(cin + base);
        *(float4*)&cv[4]  = *(const float4*)(cin + base + 4);
        *(float4*)&cv[8]  = *(const float4*)(cin + base + 8);
        *(float4*)&cv[12] = *(const float4*)(cin + base + 12);
        float sx = 0, sxx = 0, sc = 0, scc = 0;
#pragma unroll
        for (int u = 0; u < 16; u++) {
            sx += xv[u]; sxx += xv[u] * xv[u];
            sc += cv[u]; scc += cv[u] * cv[u];
        }
#pragma unroll
        for (int off = 1; off < 8; off <<= 1) {
            sx += __shfl_xor(sx, off); sxx += __shfl_xor(sxx, off);
            sc += __shfl_xor(sc, off); scc += __shfl_xor(scc, off);
        }
        const float inv = 1.0f / 128.0f;
        float mx = sx * inv, vx = sxx * inv - mx * mx, rx = rsqrtf(vx + 1e-5f);
        float mc = sc * inv, vc = scc * inv - mc * mc, rc = rsqrtf(vc + 1e-5f);
#pragma unroll
        for (int u4 = 0; u4 < 4; u4++) {
            bf16x4 xw, cwv;
#pragma unroll
            for (int i = 0; i < 4; i++) {
                int e = p8 * 16 + u4 * 4 + i;
                xw[i] = (short)f2bf((xv[u4 * 4 + i] - mx) * rx);
                cwv[i] = (short)f2bf((cv[u4 * 4 + i] - mc) * rc * cw[e]);
            }
            *(bf16x4*)&xn[r][p8 * 16 + u4 * 4] = xw;
            *(bf16x4*)&cn[r][p8 * 16 + u4 * 4] = cwv;
        }
    }
    __syncthreads();

    const int lane = t & 63, w = t >> 6;
    const int j15 = lane & 15, g = lane >> 4;

    // GEMM1: adaptive scale + bias
    f32x4 as_[4], ab_[4];
#pragma unroll
    for (int i = 0; i < 4; i++) { as_[i] = (f32x4)0.f; ab_[i] = (f32x4)0.f; }
#pragma unroll
    for (int kk = 0; kk < 8; kk++) {
        bf16x4 a = *(bf16x4*)&cn[j15][kk * 16 + 4 * g];
#pragma unroll
        for (int c2 = 0; c2 < 4; c2++) {
            int ct = w * 4 + c2;
            bf16x4 bs = *(const bf16x4*)(Wsc + (size_t)(ct * 16 + j15) * 128 + kk * 16 + 4 * g);
            bf16x4 bb = *(const bf16x4*)(Wbi + (size_t)(ct * 16 + j15) * 128 + kk * 16 + 4 * g);
            as_[c2] = mfma16(a, bs, as_[c2]);
            ab_[c2] = mfma16(a, bb, ab_[c2]);
        }
    }
#pragma unroll
    for (int c2 = 0; c2 < 4; c2++) {
        int c = (w * 4 + c2) * 16 + j15;
        float sb = slb[c];
#pragma unroll
        for (int reg = 0; reg < 4; reg++) {
            int nl = 4 * g + reg;
            float xnv = bf2f(xn[nl][c]);
            xq[nl][c] = f2bf(sigmoidf_(as_[c2][reg] + sb) * xnv + ab_[c2][reg]);
        }
    }
    __syncthreads();

    // GEMM2: w1 (q/k), w2 (gate/v)
    f32x4 o1_[4], o2_[4];
#pragma unroll
    for (int i = 0; i < 4; i++) { o1_[i] = (f32x4)0.f; o2_[i] = (f32x4)0.f; }
#pragma unroll
    for (int kk = 0; kk < 8; kk++) {
        bf16x4 a = *(bf16x4*)&xq[j15][kk * 16 + 4 * g];
#pragma unroll
        for (int c2 = 0; c2 < 4; c2++) {
            int ct = w * 4 + c2;
            bf16x4 b1 = *(const bf16x4*)(W1 + (size_t)(ct * 16 + j15) * 128 + kk * 16 + 4 * g);
            bf16x4 b2 = *(const bf16x4*)(W2 + (size_t)(ct * 16 + j15) * 128 + kk * 16 + 4 * g);
            o1_[c2] = mfma16(a, b1, o1_[c2]);
            o2_[c2] = mfma16(a, b2, o2_[c2]);
        }
    }
    const int b = rowblk >> 11, n0 = rowblk & 2047;
    if (qside) {
#pragma unroll
        for (int c2 = 0; c2 < 4; c2++) {
            int ct = w * 4 + c2;     // head = ct
            float bqv = bq[ct * 16 + j15];
#pragma unroll
            for (int reg = 0; reg < 4; reg++) {
                int n = n0 + 4 * g + reg;
                qs[(((size_t)b * 8 + ct) * 2048 + n) * 16 + j15] =
                    f2bf((o1_[c2][reg] + bqv) * 0.25f);
                gate[((size_t)b * 2048 + n) * 128 + ct * 16 + j15] = sigmoidf_(o2_[c2][reg]);
            }
        }
    } else {
#pragma unroll
        for (int c2 = 0; c2 < 4; c2++) {
            int ct = w * 4 + c2;
#pragma unroll
            for (int reg = 0; reg < 4; reg++) {
                int n = n0 + 4 * g + reg;
                ks[(((size_t)b * 8 + ct) * 2048 + n) * 16 + j15] = f2bf(o1_[c2][reg]);
                vls[ct * 16 + j15][4 * g + reg] = f2bf(o2_[c2][reg]);
            }
        }
        __syncthreads();
        // transpose write-out: thread t handles channel c = t
        const int c = t, h = c >> 4, d = c & 15;
        unsigned pk[8];
#pragma unroll
        for (int u2 = 0; u2 < 8; u2++)
            pk[u2] = (unsigned)vls[c][2 * u2] | ((unsigned)vls[c][2 * u2 + 1] << 16);
        u16* vp = vt + ((size_t)(b * 8 + h) * 16 + d) * 2048 + n0;
        *(uint4*)vp = *(uint4*)pk;
        *(uint4*)(vp + 8) = *(uint4*)(pk + 4);
    }
}

// ---------------- K2: MFMA flash attention, 1 wave / 16 q-rows (unchanged) ----------------
__global__ __launch_bounds__(64)
void attn_kernel(const u16* __restrict__ qg, const u16* __restrict__ kg,
                 const u16* __restrict__ vtg, const float* __restrict__ pair,
                 const float* __restrict__ gate, float* __restrict__ ao)
{
    __shared__ float P[16][68];
    const int l = threadIdx.x;
    const int g = l >> 4, q = l & 15;
    const int qt = blockIdx.x & 127;
    const int bh = blockIdx.x >> 7;
    const int b = bh >> 3, h = bh & 7;
    const int q0 = qt * 16;

    const u16* qb = qg + ((size_t)bh * 2048 + q0 + q) * 16 + 4 * g;
    const u16* kb = kg + ((size_t)bh * 2048 + q) * 16 + 4 * g;
    const u16* vb = vtg + ((size_t)bh * 16 + q) * 2048 + 4 * g;
    const float* pb = pair + (size_t)bh * N_ * N_ + (size_t)(q0 + g) * N_ + q * 4;

    bf16x4 qf = *(const bf16x4*)qb;

    f32x4 o = {0.f, 0.f, 0.f, 0.f};
    float m = -1e30f, lsum = 0.f;

    f32x4 p0[4], p1[4], p2[4], p3[4];
    bf16x4 k0[4], v0[4], k1[4], v1[4];

    auto issue_pair = [&](f32x4 (&pr)[4], int kt) {
        const float* pt = pb + kt * 64;
#pragma unroll
        for (int i = 0; i < 4; i++)
            pr[i] = *(const f32x4*)(pt + (size_t)(4 * i) * N_);
    };
    auto issue_kv = [&](bf16x4 (&kf)[4], bf16x4 (&vf)[4], int kt) {
#pragma unroll
        for (int tt = 0; tt < 4; tt++) {
            kf[tt] = *(const bf16x4*)(kb + (size_t)(kt * 64 + tt * 16) * 16);
            vf[tt] = *(const bf16x4*)(vb + kt * 64 + tt * 16);
        }
    };
    auto step = [&](f32x4 (&pr)[4], bf16x4 (&kf)[4], bf16x4 (&vf)[4]) {
#pragma unroll
        for (int i = 0; i < 4; i++)
            *(f32x4*)&P[g + 4 * i][q * 4] = pr[i];
        asm volatile("s_waitcnt lgkmcnt(0)" ::: "memory");
        __builtin_amdgcn_sched_barrier(0);
        f32x4 s[4];
#pragma unroll
        for (int tt = 0; tt < 4; tt++) {
            f32x4 c = *(const f32x4*)&P[q][tt * 16 + 4 * g];
            s[tt] = mfma16(kf[tt], qf, c);
        }
        float mloc = s[0][0];
#pragma unroll
        for (int tt = 0; tt < 4; tt++)
#pragma unroll
            for (int r = 0; r < 4; r++) mloc = fmaxf(mloc, s[tt][r]);
        mloc = fmaxf(mloc, __shfl_xor(mloc, 16));
        mloc = fmaxf(mloc, __shfl_xor(mloc, 32));
        float mnew = fmaxf(m, mloc);
        float fsc = __expf(m - mnew);
        m = mnew;
        lsum *= fsc;
#pragma unroll
        for (int r = 0; r < 4; r++) {
            float fr = __shfl(fsc, 4 * g + r);
            o[r] *= fr;
        }
        bf16x4 pf[4];
#pragma unroll
        for (int tt = 0; tt < 4; tt++) {
#pragma unroll
            for (int r = 0; r < 4; r++) {
                float p = __expf(s[tt][r] - mnew);
                lsum += p;
                pf[tt][r] = (short)f2bf(p);
            }
        }
#pragma unroll
        for (int tt = 0; tt < 4; tt++)
            o = mfma16(pf[tt], vf[tt], o);
    };

    issue_pair(p0, 0); issue_pair(p1, 1); issue_pair(p2, 2); issue_pair(p3, 3);
    issue_kv(k0, v0, 0); issue_kv(k1, v1, 1);

    for (int kt = 0; kt < 32; kt += 4) {
        step(p0, k0, v0);
        if (kt + 4 < 32) issue_pair(p0, kt + 4);
        if (kt + 2 < 32) issue_kv(k0, v0, kt + 2);
        step(p1, k1, v1);
        if (kt + 5 < 32) issue_pair(p1, kt + 5);
        if (kt + 3 < 32) issue_kv(k1, v1, kt + 3);
        step(p2, k0, v0);
        if (kt + 6 < 32) issue_pair(p2, kt + 6);
        if (kt + 4 < 32) issue_kv(k0, v0, kt + 4);
        step(p3, k1, v1);
        if (kt + 7 < 32) issue_pair(p3, kt + 7);
        if (kt + 5 < 32) issue_kv(k1, v1, kt + 5);
    }

    lsum += __shfl_xor(lsum, 16);
    lsum += __shfl_xor(lsum, 32);
    const size_t orow0 = (size_t)b * 2048 + q0;
#pragma unroll
    for (int r = 0; r < 4; r++) {
        float li = __shfl(lsum, 4 * g + r);
        size_t idx = (orow0 + 4 * g + r) * 128 + h * 16 + q;
        ao[idx] = o[r] * (1.0f / li) * gate[idx];
    }
}

// ---------------- K3: fused post-attention + transition, MFMA ----------------
__global__ __launch_bounds__(128)
void post_trans(const float* __restrict__ aob, const float* __restrict__ scq,
                const float* __restrict__ x_q,
                const float* __restrict__ azi_bc, const float* __restrict__ t_cond_w,
                const float* __restrict__ t_scale_b, const float* __restrict__ t_azi_bc,
                const u16* __restrict__ wT, float* __restrict__ out)
{
    __shared__ u16 aoL[16][132];
    __shared__ u16 scL[16][132];
    __shared__ u16 cnL[16][132];
    __shared__ u16 ynL[16][132];
    __shared__ u16 aaL[16][132];
    __shared__ float yL[16][132];
    __shared__ u16 hL[16][520];
    const int rowblk = blockIdx.x * 16;
    const int t = threadIdx.x, lane = t & 63, w = t >> 6;
    const int j15 = lane & 15, g = lane >> 4;

    {   // P0: stage ao/sc, LN(scq)*t_cond_w
        const int r = t >> 3, p8 = t & 7;
        const size_t base = (size_t)(rowblk + r) * 128 + p8 * 16;
        float av[16], cv[16];
        *(float4*)&av[0]  = *(const float4*)(aob + base);
        *(float4*)&av[4]  = *(const float4*)(aob + base + 4);
        *(float4*)&av[8]  = *(const float4*)(aob + base + 8);
        *(float4*)&av[12] = *(const float4*)(aob + base + 12);
        *(float4*)&cv[0]  = *(const float4*)(scq + base);
        *(float4*)&cv[4]  = *(const float4*)(scq + base + 4);
        *(float4*)&cv[8]  = *(const float4*)(scq + base + 8);
        *(float4*)&cv[12] = *(const float4*)(scq + base + 12);
        float sc = 0, scc = 0;
#pragma unroll
        for (int u = 0; u < 16; u++) { sc += cv[u]; scc += cv[u] * cv[u]; }
#pragma unroll
        for (int off = 1; off < 8; off <<= 1) {
            sc += __shfl_xor(sc, off); scc += __shfl_xor(scc, off);
        }
        const float inv = 1.0f / 128.0f;
        float mc = sc * inv, vc = scc * inv - mc * mc, rc = rsqrtf(vc + 1e-5f);
#pragma unroll
        for (int u = 0; u < 16; u++) {
            int e = p8 * 16 + u;
            aoL[r][e] = f2bf(av[u]);
            scL[r][e] = f2bf(cv[u]);
            cnL[r][e] = f2bf((cv[u] - mc) * rc * t_cond_w[e]);
        }
    }
    __syncthreads();

    // GEMM-A: at = ao @ azi_wt^T ; ac = sc @ azi_wc^T
    f32x4 at_[4], ac_[4];
#pragma unroll
    for (int i = 0; i < 4; i++) { at_[i] = (f32x4)0.f; ac_[i] = (f32x4)0.f; }
    {
        const u16* Bt = wT + WT_AZIT;
        const u16* Bc = wT + WT_AZIC;
#pragma unroll
        for (int kk = 0; kk < 8; kk++) {
            bf16x4 a1 = *(bf16x4*)&aoL[j15][kk * 16 + 4 * g];
            bf16x4 a2 = *(bf16x4*)&scL[j15][kk * 16 + 4 * g];
#pragma unroll
            for (int c2 = 0; c2 < 4; c2++) {
                int ct = w * 4 + c2;
                bf16x4 bt = *(const bf16x4*)(Bt + (size_t)(ct * 16 + j15) * 128 + kk * 16 + 4 * g);
                bf16x4 bc2 = *(const bf16x4*)(Bc + (size_t)(ct * 16 + j15) * 128 + kk * 16 + 4 * g);
                at_[c2] = mfma16(a1, bt, at_[c2]);
                ac_[c2] = mfma16(a2, bc2, ac_[c2]);
            }
        }
    }
#pragma unroll
    for (int c2 = 0; c2 < 4; c2++) {
        int c = (w * 4 + c2) * 16 + j15;
        float bc0 = azi_bc[c];
#pragma unroll
        for (int reg = 0; reg < 4; reg++) {
            int nl = 4 * g + reg;
            size_t gi = (size_t)(rowblk + nl) * 128 + c;
            yL[nl][c] = x_q[gi] + sigmoidf_(ac_[c2][reg] + bc0) * at_[c2][reg];
        }
    }
    __syncthreads();

    {   // LN(y)
        const int r = t >> 3, p8 = t & 7;
        float yv[16];
        *(float4*)&yv[0]  = *(float4*)&yL[r][p8 * 16];
        *(float4*)&yv[4]  = *(float4*)&yL[r][p8 * 16 + 4];
        *(float4*)&yv[8]  = *(float4*)&yL[r][p8 * 16 + 8];
        *(float4*)&yv[12] = *(float4*)&yL[r][p8 * 16 + 12];
        float sy = 0, syy = 0;
#pragma unroll
        for (int u = 0; u < 16; u++) { sy += yv[u]; syy += yv[u] * yv[u]; }
#pragma unroll
        for (int off = 1; off < 8; off <<= 1) {
            sy += __shfl_xor(sy, off); syy += __shfl_xor(syy, off);
        }
        const float inv = 1.0f / 128.0f;
        float my = sy * inv, vy = syy * inv - my * my, ry = rsqrtf(vy + 1e-5f);
#pragma unroll
        for (int u = 0; u < 16; u++)
            ynL[r][p8 * 16 + u] = f2bf((yv[u] - my) * ry);
    }
    __syncthreads();

    // GEMM-B: as(t_scale), ab(t_bias) from cn; atg(t_azi_wc) from sc
    f32x4 s_[4], b_[4], g_[4], tg_[4];
#pragma unroll
    for (int i = 0; i < 4; i++) { s_[i] = (f32x4)0.f; b_[i] = (f32x4)0.f; g_[i] = (f32x4)0.f; }
    {
        const u16* Bs = wT + WT_TS;
        const u16* Bb = wT + WT_TB;
        const u16* Bg = wT + WT_TAZIC;
#pragma unroll
        for (int kk = 0; kk < 8; kk++) {
            bf16x4 a1 = *(bf16x4*)&cnL[j15][kk * 16 + 4 * g];
            bf16x4 a2 = *(bf16x4*)&scL[j15][kk * 16 + 4 * g];
#pragma unroll
            for (int c2 = 0; c2 < 4; c2++) {
                int ct = w * 4 + c2;
                bf16x4 bs = *(const bf16x4*)(Bs + (size_t)(ct * 16 + j15) * 128 + kk * 16 + 4 * g);
                bf16x4 bb = *(const bf16x4*)(Bb + (size_t)(ct * 16 + j15) * 128 + kk * 16 + 4 * g);
                bf16x4 bg = *(const bf16x4*)(Bg + (size_t)(ct * 16 + j15) * 128 + kk * 16 + 4 * g);
                s_[c2] = mfma16(a1, bs, s_[c2]);
                b_[c2] = mfma16(a1, bb, b_[c2]);
                g_[c2] = mfma16(a2, bg, g_[c2]);
            }
        }
    }
#pragma unroll
    for (int c2 = 0; c2 < 4; c2++) {
        int c = (w * 4 + c2) * 16 + j15;
        float sb = t_scale_b[c], tb = t_azi_bc[c];
#pragma unroll
        for (int reg = 0; reg < 4; reg++) {
            int nl = 4 * g + reg;
            aaL[nl][c] = f2bf(sigmoidf_(s_[c2][reg] + sb) * bf2f(ynL[nl][c]) + b_[c2][reg]);
            tg_[c2][reg] = sigmoidf_(g_[c2][reg] + tb);
        }
    }
    __syncthreads();

    // GEMM-C: h = silu(aa@glu1^T) * (aa@glu2^T), 512 cols; wave w covers ct w*16..w*16+15
    {
        const u16* G1 = wT + WT_GLU1;
        const u16* G2 = wT + WT_GLU2;
        for (int pass = 0; pass < 2; pass++) {
            f32x4 h1_[8], h2_[8];
#pragma unroll
            for (int i = 0; i < 8; i++) { h1_[i] = (f32x4)0.f; h2_[i] = (f32x4)0.f; }
#pragma unroll
            for (int kk = 0; kk < 8; kk++) {
                bf16x4 a = *(bf16x4*)&aaL[j15][kk * 16 + 4 * g];
#pragma unroll
                for (int u = 0; u < 8; u++) {
                    int ct = w * 16 + pass * 8 + u;
                    bf16x4 b1 = *(const bf16x4*)(G1 + (size_t)(ct * 16 + j15) * 128 + kk * 16 + 4 * g);
                    bf16x4 b2 = *(const bf16x4*)(G2 + (size_t)(ct * 16 + j15) * 128 + kk * 16 + 4 * g);
                    h1_[u] = mfma16(a, b1, h1_[u]);
                    h2_[u] = mfma16(a, b2, h2_[u]);
                }
            }
#pragma unroll
            for (int u = 0; u < 8; u++) {
                int c = (w * 16 + pass * 8 + u) * 16 + j15;
#pragma unroll
                for (int reg = 0; reg < 4; reg++) {
                    int nl = 4 * g + reg;
                    float hv1 = h1_[u][reg];
                    hL[nl][c] = f2bf(hv1 * sigmoidf_(hv1) * h2_[u][reg]);
                }
            }
        }
    }
    __syncthreads();

    // GEMM-D: t = h @ t_azi_wt^T, K=512
    f32x4 td_[4];
#pragma unroll
    for (int i = 0; i < 4; i++) td_[i] = (f32x4)0.f;
    {
        const u16* W4 = wT + WT_TAZIT;   // [128][512]
#pragma unroll 4
        for (int kk = 0; kk < 32; kk++) {
            bf16x4 a = *(bf16x4*)&hL[j15][kk * 16 + 4 * g];
#pragma unroll
            for (int c2 = 0; c2 < 4; c2++) {
                int ct = w * 4 + c2;
                bf16x4 b = *(const bf16x4*)(W4 + (size_t)(ct * 16 + j15) * 512 + kk * 16 + 4 * g);
                td_[c2] = mfma16(a, b, td_[c2]);
            }
        }
    }
#pragma unroll
    for (int c2 = 0; c2 < 4; c2++) {
        int c = (w * 4 + c2) * 16 + j15;
#pragma unroll
        for (int reg = 0; reg < 4; reg++) {
            int nl = 4 * g + reg;
            size_t gi = (size_t)(rowblk + nl) * 128 + c;
            out[gi] = yL[nl][c] + tg_[c2][reg] * td_[c2][reg];
        }
    }
}

extern "C" void kernel_launch(void* const* d_in, const int* in_sizes, int n_in,
                              void* d_out, int out_size, void* d_ws, size_t ws_size,
                              hipStream_t stream)
{
    (void)in_sizes; (void)n_in; (void)out_size; (void)ws_size;
    const float* x_q      = (const float*)d_in[0];
    const float* x_k      = (const float*)d_in[1];
    const float* pair     = (const float*)d_in[4];
    const float* scq      = (const float*)d_in[5];
    const float* sck      = (const float*)d_in[6];
    const float* q_cond_w = (const float*)d_in[7];
    const float* q_scale_w= (const float*)d_in[8];
    const float* q_scale_b= (const float*)d_in[9];
    const float* q_bias_w = (const float*)d_in[10];
    const float* k_cond_w = (const float*)d_in[11];
    const float* k_scale_w= (const float*)d_in[12];
    const float* k_scale_b= (const float*)d_in[13];
    const float* k_bias_w = (const float*)d_in[14];
    const float* wq       = (const float*)d_in[15];
    const float* bq       = (const float*)d_in[16];
    const float* wk       = (const float*)d_in[17];
    const float* wv       = (const float*)d_in[18];
    const float* wg       = (const float*)d_in[19];
    const float* azi_wt   = (const float*)d_in[20];
    const float* azi_wc   = (const float*)d_in[21];
    const float* azi_bc   = (const float*)d_in[22];
    const float* t_cond_w = (const float*)d_in[23];
    const float* t_scale_w= (const float*)d_in[24];
    const float* t_scale_b= (const float*)d_in[25];
    const float* t_bias_w = (const float*)d_in[26];
    const float* glu1     = (const float*)d_in[27];
    const float* glu2     = (const float*)d_in[28];
    const float* t_azi_wt = (const float*)d_in[29];
    const float* t_azi_wc = (const float*)d_in[30];
    const float* t_azi_bc = (const float*)d_in[31];

    float* out = (float*)d_out;
    u16* qs = (u16*)d_ws;                    // bf16 [16][2048][16]   1MB
    u16* ks = qs + 524288;                   // 1MB
    u16* vt = ks + 524288;                   // bf16 [16][16][2048]   1MB
    float* gate = (float*)(vt + 524288);     // f32 [4096][128]       2MB
    float* aob  = gate + 524288;             // f32 [4096][128]       2MB
    u16* wT = (u16*)(aob + 524288);          // bf16 weights^T        0.8MB

    prep_kernel<<<25, 256, 0, stream>>>(
        q_scale_w, q_bias_w, wq, wg, k_scale_w, k_bias_w, wk, wv,
        azi_wt, azi_wc, t_scale_w, t_bias_w, t_azi_wc, glu1, glu2, t_azi_wt, wT);
    adaln_mfma<<<512, 128, 0, stream>>>(
        x_q, scq, x_k, sck, q_cond_w, q_scale_b, bq, k_cond_w, k_scale_b,
        wT, qs, ks, vt, gate);
    attn_kernel<<<B_ * H_ * (N_ / 16), 64, 0, stream>>>(qs, ks, vt, pair, gate, aob);
    post_trans<<<NROW / 16, 128, 0, stream>>>(
        aob, scq, x_q, azi_bc, t_cond_w, t_scale_b, t_azi_bc, wT, out);
}